// Round 2
// baseline (797.914 us; speedup 1.0000x reference)
//
#include <hip/hip_runtime.h>

// GRUAdder: B=1048576 sequences, T=4, I=2, H=16.
// v3: 1 element/thread, fully unrolled, PAIR-BUFFERED hidden stores.
//   - hidden_table lines are 128B = (t,t+1) chunks of one element. Writing
//     them per-t splits every line across ~2500 dynamic instructions ->
//     L2 evicts partially-dirty lines -> RMW fetch (v2: 384MB fetch, 1GB write).
//     Here h(t0),h(t1) are both kept live and written as one contiguous
//     128B-aligned line-complete burst; same for (t2,t3). amp -> 1.
//   - 1 elem/thread restores perfectly-coalesced sum/carry/logit stores.
//   - launch_bounds(256,6): peak liveness ~70 floats fits 84 VGPR,
//     6 waves/SIMD for latency hiding (v2 was 4).

constexpr long long Bn = 1048576;
constexpr int Hn = 16;

__device__ __forceinline__ float sigm_f(float x) {
    // 1 / (1 + e^-x)
    return __builtin_amdgcn_rcpf(1.0f + __expf(-x));
}
__device__ __forceinline__ float tanh_f(float x) {
    // tanh(x) = 1 - 2/(e^{2x}+1)
    return 1.0f - 2.0f * __builtin_amdgcn_rcpf(1.0f + __expf(2.0f * x));
}

// One GRU step with h == 0 (t = 0): gh == b_hh, skips the 768 h@W_hh FMAs.
__device__ __forceinline__ void gru_step0(
    float x0, float x1,
    const float* __restrict__ w_ih, const float* __restrict__ b_ih,
    const float* __restrict__ b_hh, float (&h)[Hn])
{
#pragma unroll
    for (int j = 0; j < Hn; ++j) {
        const float ir  = fmaf(x1, w_ih[(j)      * 2 + 1], fmaf(x0, w_ih[(j)      * 2], b_ih[j]));
        const float iz  = fmaf(x1, w_ih[(16 + j) * 2 + 1], fmaf(x0, w_ih[(16 + j) * 2], b_ih[16 + j]));
        const float inn = fmaf(x1, w_ih[(32 + j) * 2 + 1], fmaf(x0, w_ih[(32 + j) * 2], b_ih[32 + j]));
        const float r = sigm_f(ir + b_hh[j]);
        const float z = sigm_f(iz + b_hh[16 + j]);
        const float n = tanh_f(fmaf(r, b_hh[32 + j], inn));
        h[j] = n - z * n;  // (1-z)*n + z*0
    }
}

// Full GRU step: hn = GRUCell(x, h).
__device__ __forceinline__ void gru_step(
    float x0, float x1,
    const float* __restrict__ w_ih, const float* __restrict__ w_hh,
    const float* __restrict__ b_ih, const float* __restrict__ b_hh,
    const float (&h)[Hn], float (&hn)[Hn])
{
#pragma unroll
    for (int j = 0; j < Hn; ++j) {
        const float ir  = fmaf(x1, w_ih[(j)      * 2 + 1], fmaf(x0, w_ih[(j)      * 2], b_ih[j]));
        const float iz  = fmaf(x1, w_ih[(16 + j) * 2 + 1], fmaf(x0, w_ih[(16 + j) * 2], b_ih[16 + j]));
        const float inn = fmaf(x1, w_ih[(32 + j) * 2 + 1], fmaf(x0, w_ih[(32 + j) * 2], b_ih[32 + j]));
        float hr = b_hh[j];
        float hz = b_hh[16 + j];
        float hg = b_hh[32 + j];
#pragma unroll
        for (int k = 0; k < Hn; ++k) {
            const float hk = h[k];
            hr = fmaf(hk, w_hh[(j)      * 16 + k], hr);
            hz = fmaf(hk, w_hh[(16 + j) * 16 + k], hz);
            hg = fmaf(hk, w_hh[(32 + j) * 16 + k], hg);
        }
        const float r = sigm_f(ir + hr);
        const float z = sigm_f(iz + hz);
        const float n = tanh_f(fmaf(r, hg, inn));
        hn[j] = fmaf(z, h[j] - n, n);  // (1-z)*n + z*h
    }
}

// 4-way-split dot product (breaks the 16-long serial FMA chain).
__device__ __forceinline__ float dot16_bias(
    const float (&h)[Hn], const float* __restrict__ w, float bias)
{
    float s0 = bias, s1 = 0.0f, s2 = 0.0f, s3 = 0.0f;
#pragma unroll
    for (int k = 0; k < Hn; k += 4) {
        s0 = fmaf(h[k + 0], w[k + 0], s0);
        s1 = fmaf(h[k + 1], w[k + 1], s1);
        s2 = fmaf(h[k + 2], w[k + 2], s2);
        s3 = fmaf(h[k + 3], w[k + 3], s3);
    }
    return (s0 + s1) + (s2 + s3);
}

// Write (h_even, h_odd) = 32 floats = one full 128B-aligned L2 line,
// back-to-back -> line-complete, no RMW, no write amplification.
__device__ __forceinline__ void store_pair(
    float* __restrict__ dst, const float (&he)[Hn], const float (&ho)[Hn])
{
    float4* p = (float4*)dst;
    p[0] = make_float4(he[0],  he[1],  he[2],  he[3]);
    p[1] = make_float4(he[4],  he[5],  he[6],  he[7]);
    p[2] = make_float4(he[8],  he[9],  he[10], he[11]);
    p[3] = make_float4(he[12], he[13], he[14], he[15]);
    p[4] = make_float4(ho[0],  ho[1],  ho[2],  ho[3]);
    p[5] = make_float4(ho[4],  ho[5],  ho[6],  ho[7]);
    p[6] = make_float4(ho[8],  ho[9],  ho[10], ho[11]);
    p[7] = make_float4(ho[12], ho[13], ho[14], ho[15]);
}

__global__ __launch_bounds__(256, 6) void gru_adder_kernel(
    const float* __restrict__ x_bits,   // [B, 4, 2]
    const float* __restrict__ w_ih,     // [48, 2]
    const float* __restrict__ w_hh,     // [48, 16]
    const float* __restrict__ b_ih,     // [48]
    const float* __restrict__ b_hh,     // [48]
    const float* __restrict__ w_sum,    // [1, 16]
    const float* __restrict__ b_sum,    // [1]
    const float* __restrict__ w_carry,  // [1, 16]
    const float* __restrict__ b_carry,  // [1]
    float* __restrict__ out)            // [64B | 4B | B | 5B] floats
{
    const long long b = (long long)blockIdx.x * blockDim.x + threadIdx.x;

    // This sequence's 8 input floats (32B-aligned, two float4).
    const float4* xp = (const float4*)(x_bits + b * 8);
    const float4 xv0 = xp[0];
    const float4 xv1 = xp[1];

    const float bs = b_sum[0];

    // ---- t = 0 (h == 0 specialization) and t = 1 ----
    float h0[Hn], h1[Hn];
    gru_step0(xv0.x, xv0.y, w_ih, b_ih, b_hh, h0);
    const float s0 = dot16_bias(h0, w_sum, bs);
    gru_step(xv0.z, xv0.w, w_ih, w_hh, b_ih, b_hh, h0, h1);
    const float s1 = dot16_bias(h1, w_sum, bs);

    // hidden_table[b][0..1][:] — one full 128B line.
    store_pair(out + b * 64, h0, h1);

    // ---- t = 2 and t = 3 ----
    float h2[Hn], h3[Hn];
    gru_step(xv1.x, xv1.y, w_ih, w_hh, b_ih, b_hh, h1, h2);
    const float s2 = dot16_bias(h2, w_sum, bs);
    gru_step(xv1.z, xv1.w, w_ih, w_hh, b_ih, b_hh, h2, h3);
    const float s3 = dot16_bias(h3, w_sum, bs);

    // hidden_table[b][2..3][:] — second full 128B line.
    store_pair(out + b * 64 + 32, h2, h3);

    // carry logit from final h
    const float c = dot16_bias(h3, w_carry, b_carry[0]);

    // sum_logits [B,4] at offset 64*B — float4, 16B lane stride, fully coalesced.
    *(float4*)(out + 64ll * Bn + b * 4) = make_float4(s0, s1, s2, s3);

    // carry_logit [B,1] at offset 68*B — 4B lane stride, coalesced.
    out[68ll * Bn + b] = c;

    // output_logits [B,5] at offset 69*B — 20B lane stride; the 5 adjacent
    // scalar stores cover a contiguous 1280B wave region -> lines complete.
    float* ol = out + 69ll * Bn + b * 5;
    ol[0] = s0;
    ol[1] = s1;
    ol[2] = s2;
    ol[3] = s3;
    ol[4] = c;
}

extern "C" void kernel_launch(void* const* d_in, const int* in_sizes, int n_in,
                              void* d_out, int out_size, void* d_ws, size_t ws_size,
                              hipStream_t stream) {
    const float* x_bits  = (const float*)d_in[0];
    const float* w_ih    = (const float*)d_in[1];
    const float* w_hh    = (const float*)d_in[2];
    const float* b_ih    = (const float*)d_in[3];
    const float* b_hh    = (const float*)d_in[4];
    const float* w_sum   = (const float*)d_in[5];
    const float* b_sum   = (const float*)d_in[6];
    const float* w_carry = (const float*)d_in[7];
    const float* b_carry = (const float*)d_in[8];
    float* out = (float*)d_out;

    const int block = 256;
    const int grid = (int)((Bn + block - 1) / block);  // 4096
    gru_adder_kernel<<<grid, block, 0, stream>>>(
        x_bits, w_ih, w_hh, b_ih, b_hh, w_sum, b_sum, w_carry, b_carry, out);
}

// Round 3
// 654.922 us; speedup vs baseline: 1.2183x; 1.2183x over previous
//
#include <hip/hip_runtime.h>

// GRUAdder: B=1048576 sequences, T=4, I=2, H=16.
// v4: all three proven levers at once, spill-free.
//  - 2 batch elements/thread  (v1->v2: -36%, the ILP lever)
//  - rolled t-loop            (~24KB code, 3x I$ reuse)
//  - pair-buffered hidden stores: (h_t, h_t+1) written as one 128B
//    line-complete burst, protected by an asm memory fence so the
//    compiler cannot re-split it (v3 failure: VGPR=40 squeeze re-split
//    the burst -> 479MB RMW fetch)
//  - launch_bounds(256,4): 128-VGPR budget, peak liveness ~110, so the
//    allocator has headroom and never trades the store pattern away.
//  - sum/carry/logit values held in shift-register scalars (no
//    runtime-indexed arrays -> no scratch), stored once, contiguous.

constexpr long long Bn = 1048576;
constexpr int Hn = 16;

__device__ __forceinline__ float sigm_f(float x) {
    return __builtin_amdgcn_rcpf(1.0f + __expf(-x));
}
__device__ __forceinline__ float tanh_f(float x) {
    return 1.0f - 2.0f * __builtin_amdgcn_rcpf(1.0f + __expf(2.0f * x));
}

// t = 0 step (h == 0): gh == b_hh, skips the 768 h@W_hh FMAs.
__device__ __forceinline__ void gru_step0(
    float x0, float x1,
    const float* __restrict__ w_ih, const float* __restrict__ b_ih,
    const float* __restrict__ b_hh, float (&h)[Hn])
{
#pragma unroll
    for (int j = 0; j < Hn; ++j) {
        const float ir  = fmaf(x1, w_ih[(j)      * 2 + 1], fmaf(x0, w_ih[(j)      * 2], b_ih[j]));
        const float iz  = fmaf(x1, w_ih[(16 + j) * 2 + 1], fmaf(x0, w_ih[(16 + j) * 2], b_ih[16 + j]));
        const float inn = fmaf(x1, w_ih[(32 + j) * 2 + 1], fmaf(x0, w_ih[(32 + j) * 2], b_ih[32 + j]));
        const float r = sigm_f(ir + b_hh[j]);
        const float z = sigm_f(iz + b_hh[16 + j]);
        const float n = tanh_f(fmaf(r, b_hh[32 + j], inn));
        h[j] = n - z * n;  // (1-z)*n + z*0
    }
}

// Full GRU step: hn = GRUCell(x, h).
__device__ __forceinline__ void gru_step(
    float x0, float x1,
    const float* __restrict__ w_ih, const float* __restrict__ w_hh,
    const float* __restrict__ b_ih, const float* __restrict__ b_hh,
    const float (&h)[Hn], float (&hn)[Hn])
{
#pragma unroll
    for (int j = 0; j < Hn; ++j) {
        const float ir  = fmaf(x1, w_ih[(j)      * 2 + 1], fmaf(x0, w_ih[(j)      * 2], b_ih[j]));
        const float iz  = fmaf(x1, w_ih[(16 + j) * 2 + 1], fmaf(x0, w_ih[(16 + j) * 2], b_ih[16 + j]));
        const float inn = fmaf(x1, w_ih[(32 + j) * 2 + 1], fmaf(x0, w_ih[(32 + j) * 2], b_ih[32 + j]));
        float hr = b_hh[j];
        float hz = b_hh[16 + j];
        float hg = b_hh[32 + j];
#pragma unroll
        for (int k = 0; k < Hn; ++k) {
            const float hk = h[k];
            hr = fmaf(hk, w_hh[(j)      * 16 + k], hr);
            hz = fmaf(hk, w_hh[(16 + j) * 16 + k], hz);
            hg = fmaf(hk, w_hh[(32 + j) * 16 + k], hg);
        }
        const float r = sigm_f(ir + hr);
        const float z = sigm_f(iz + hz);
        const float n = tanh_f(fmaf(r, hg, inn));
        hn[j] = fmaf(z, h[j] - n, n);  // (1-z)*n + z*h
    }
}

__device__ __forceinline__ float dot16_bias(
    const float (&h)[Hn], const float* __restrict__ w, float bias)
{
    float s0 = bias, s1 = 0.0f, s2 = 0.0f, s3 = 0.0f;
#pragma unroll
    for (int k = 0; k < Hn; k += 4) {
        s0 = fmaf(h[k + 0], w[k + 0], s0);
        s1 = fmaf(h[k + 1], w[k + 1], s1);
        s2 = fmaf(h[k + 2], w[k + 2], s2);
        s3 = fmaf(h[k + 3], w[k + 3], s3);
    }
    return (s0 + s1) + (s2 + s3);
}

// One full 128B-aligned L2 line (32 floats), back-to-back.
__device__ __forceinline__ void store_pair(
    float* __restrict__ dst, const float (&he)[Hn], const float (&ho)[Hn])
{
    float4* p = (float4*)dst;
    p[0] = make_float4(he[0],  he[1],  he[2],  he[3]);
    p[1] = make_float4(he[4],  he[5],  he[6],  he[7]);
    p[2] = make_float4(he[8],  he[9],  he[10], he[11]);
    p[3] = make_float4(he[12], he[13], he[14], he[15]);
    p[4] = make_float4(ho[0],  ho[1],  ho[2],  ho[3]);
    p[5] = make_float4(ho[4],  ho[5],  ho[6],  ho[7]);
    p[6] = make_float4(ho[8],  ho[9],  ho[10], ho[11]);
    p[7] = make_float4(ho[12], ho[13], ho[14], ho[15]);
}

__global__ __launch_bounds__(256, 4) void gru_adder_kernel(
    const float* __restrict__ x_bits,   // [B, 4, 2]
    const float* __restrict__ w_ih,     // [48, 2]
    const float* __restrict__ w_hh,     // [48, 16]
    const float* __restrict__ b_ih,     // [48]
    const float* __restrict__ b_hh,     // [48]
    const float* __restrict__ w_sum,    // [1, 16]
    const float* __restrict__ b_sum,    // [1]
    const float* __restrict__ w_carry,  // [1, 16]
    const float* __restrict__ b_carry,  // [1]
    float* __restrict__ out)            // [64B | 4B | B | 5B] floats
{
    const long long g  = (long long)blockIdx.x * blockDim.x + threadIdx.x;
    const long long b0 = 2 * g;  // batch elements b0 and b0+1

    // 16 consecutive x floats: both elements' full sequences, 64B/lane.
    const float4* xp = (const float4*)(x_bits + b0 * 8);
    const float4 v0 = xp[0], v1 = xp[1];  // elem A: t0..t3
    const float4 v2 = xp[2], v3 = xp[3];  // elem B: t0..t3

    const float bs = b_sum[0];

    float ha[Hn], hb[Hn];

    // ---- t = 0 (h == 0 specialization) ----
    gru_step0(v0.x, v0.y, w_ih, b_ih, b_hh, ha);
    gru_step0(v2.x, v2.y, w_ih, b_ih, b_hh, hb);

    // sum-logit shift queues (q3=t0 .. q0=t3 after all 4 pushes)
    float saq0 = dot16_bias(ha, w_sum, bs), saq1, saq2, saq3;
    float sbq0 = dot16_bias(hb, w_sum, bs), sbq1, sbq2, sbq3;
    saq1 = saq2 = saq3 = 0.0f;
    sbq1 = sbq2 = sbq3 = 0.0f;

    // x shift-register queues (no runtime-indexed arrays).
    float qa0 = v0.z, qa1 = v0.w, qa2 = v1.x, qa3 = v1.y, qa4 = v1.z, qa5 = v1.w;
    float qb0 = v2.z, qb1 = v2.w, qb2 = v3.x, qb3 = v3.y, qb4 = v3.z, qb5 = v3.w;

    // ---- t = 1..3, rolled ----
#pragma unroll 1
    for (int t = 1; t < 4; ++t) {
        float na[Hn], nb[Hn];
        gru_step(qa0, qa1, w_ih, w_hh, b_ih, b_hh, ha, na);
        gru_step(qb0, qb1, w_ih, w_hh, b_ih, b_hh, hb, nb);

        // push sums
        saq3 = saq2; saq2 = saq1; saq1 = saq0; saq0 = dot16_bias(na, w_sum, bs);
        sbq3 = sbq2; sbq2 = sbq1; sbq1 = sbq0; sbq0 = dot16_bias(nb, w_sum, bs);

        if (t != 2) {
            // (h_{t-1}, h_t) for both elements: two full 128B lines.
            // Fence: stores may not be hoisted above this point, so the
            // burst cannot be re-split by the scheduler (v3 failure mode).
            asm volatile("" ::: "memory");
            float* base = out + b0 * 64 + (t == 1 ? 0 : 32);
            store_pair(base,      ha, na);  // elem A line
            store_pair(base + 64, hb, nb);  // elem B line
        }

#pragma unroll
        for (int j = 0; j < Hn; ++j) { ha[j] = na[j]; hb[j] = nb[j]; }

        // advance x queues
        qa0 = qa2; qa1 = qa3; qa2 = qa4; qa3 = qa5;
        qb0 = qb2; qb1 = qb3; qb2 = qb4; qb3 = qb5;
    }

    // ---- carry logits from final h ----
    const float bc = b_carry[0];
    const float ca = dot16_bias(ha, w_carry, bc);
    const float cb = dot16_bias(hb, w_carry, bc);

    // sum_logits [B,4]: 8 contiguous floats/thread, 32B-aligned.
    float4* sp = (float4*)(out + 64ll * Bn + b0 * 4);
    sp[0] = make_float4(saq3, saq2, saq1, saq0);  // elem A: t0..t3
    sp[1] = make_float4(sbq3, sbq2, sbq1, sbq0);  // elem B: t0..t3

    // carry_logit [B,1]: float2, 8B-aligned.
    *(float2*)(out + 68ll * Bn + b0) = make_float2(ca, cb);

    // output_logits [B,5]: 10 contiguous floats/thread, 8B-aligned.
    float2* ol = (float2*)(out + 69ll * Bn + b0 * 5);
    ol[0] = make_float2(saq3, saq2);
    ol[1] = make_float2(saq1, saq0);
    ol[2] = make_float2(ca,   sbq3);
    ol[3] = make_float2(sbq2, sbq1);
    ol[4] = make_float2(sbq0, cb);
}

extern "C" void kernel_launch(void* const* d_in, const int* in_sizes, int n_in,
                              void* d_out, int out_size, void* d_ws, size_t ws_size,
                              hipStream_t stream) {
    const float* x_bits  = (const float*)d_in[0];
    const float* w_ih    = (const float*)d_in[1];
    const float* w_hh    = (const float*)d_in[2];
    const float* b_ih    = (const float*)d_in[3];
    const float* b_hh    = (const float*)d_in[4];
    const float* w_sum   = (const float*)d_in[5];
    const float* b_sum   = (const float*)d_in[6];
    const float* w_carry = (const float*)d_in[7];
    const float* b_carry = (const float*)d_in[8];
    float* out = (float*)d_out;

    const int block = 256;
    const long long threads = Bn / 2;                       // 2 elems/thread
    const int grid = (int)((threads + block - 1) / block);  // 2048
    gru_adder_kernel<<<grid, block, 0, stream>>>(
        x_bits, w_ih, w_hh, b_ih, b_hh, w_sum, b_sum, w_carry, b_carry, out);
}

// Round 4
// 650.447 us; speedup vs baseline: 1.2267x; 1.0069x over previous
//
#include <hip/hip_runtime.h>

// GRUAdder: B=1048576 sequences, T=4, I=2, H=16.
// v5 = v4 + amdgpu_waves_per_eu(4,4).
// v2/v4 post-mortem: __launch_bounds__(256,4) only sets MIN waves/EU; the
// backend's occupancy heuristic still register-minimized to 64 VGPRs
// (the 8-waves/SIMD step) and spilled the ~110-float live state to
// scratch (v4: FETCH excess 113MB ~= 215B/thread reload, WRITE excess
// 327MB, occupancy scratch-capped at 43%). Clamping max waves/EU to 4
// removes the allocator's incentive to squeeze: budget 128 VGPRs,
// state fits, zero scratch.
//  - 2 batch elements/thread (ILP lever, v1->v2 -36%)
//  - rolled t-loop (I$ reuse)
//  - pair-buffered 128B line-complete hidden stores (no L2 RMW)
//  - contiguous per-thread sum/carry/logit stores

constexpr long long Bn = 1048576;
constexpr int Hn = 16;

__device__ __forceinline__ float sigm_f(float x) {
    return __builtin_amdgcn_rcpf(1.0f + __expf(-x));
}
__device__ __forceinline__ float tanh_f(float x) {
    return 1.0f - 2.0f * __builtin_amdgcn_rcpf(1.0f + __expf(2.0f * x));
}

// t = 0 step (h == 0): gh == b_hh, skips the 768 h@W_hh FMAs.
__device__ __forceinline__ void gru_step0(
    float x0, float x1,
    const float* __restrict__ w_ih, const float* __restrict__ b_ih,
    const float* __restrict__ b_hh, float (&h)[Hn])
{
#pragma unroll
    for (int j = 0; j < Hn; ++j) {
        const float ir  = fmaf(x1, w_ih[(j)      * 2 + 1], fmaf(x0, w_ih[(j)      * 2], b_ih[j]));
        const float iz  = fmaf(x1, w_ih[(16 + j) * 2 + 1], fmaf(x0, w_ih[(16 + j) * 2], b_ih[16 + j]));
        const float inn = fmaf(x1, w_ih[(32 + j) * 2 + 1], fmaf(x0, w_ih[(32 + j) * 2], b_ih[32 + j]));
        const float r = sigm_f(ir + b_hh[j]);
        const float z = sigm_f(iz + b_hh[16 + j]);
        const float n = tanh_f(fmaf(r, b_hh[32 + j], inn));
        h[j] = n - z * n;  // (1-z)*n + z*0
    }
}

// Full GRU step: hn = GRUCell(x, h).
__device__ __forceinline__ void gru_step(
    float x0, float x1,
    const float* __restrict__ w_ih, const float* __restrict__ w_hh,
    const float* __restrict__ b_ih, const float* __restrict__ b_hh,
    const float (&h)[Hn], float (&hn)[Hn])
{
#pragma unroll
    for (int j = 0; j < Hn; ++j) {
        const float ir  = fmaf(x1, w_ih[(j)      * 2 + 1], fmaf(x0, w_ih[(j)      * 2], b_ih[j]));
        const float iz  = fmaf(x1, w_ih[(16 + j) * 2 + 1], fmaf(x0, w_ih[(16 + j) * 2], b_ih[16 + j]));
        const float inn = fmaf(x1, w_ih[(32 + j) * 2 + 1], fmaf(x0, w_ih[(32 + j) * 2], b_ih[32 + j]));
        float hr = b_hh[j];
        float hz = b_hh[16 + j];
        float hg = b_hh[32 + j];
#pragma unroll
        for (int k = 0; k < Hn; ++k) {
            const float hk = h[k];
            hr = fmaf(hk, w_hh[(j)      * 16 + k], hr);
            hz = fmaf(hk, w_hh[(16 + j) * 16 + k], hz);
            hg = fmaf(hk, w_hh[(32 + j) * 16 + k], hg);
        }
        const float r = sigm_f(ir + hr);
        const float z = sigm_f(iz + hz);
        const float n = tanh_f(fmaf(r, hg, inn));
        hn[j] = fmaf(z, h[j] - n, n);  // (1-z)*n + z*h
    }
}

__device__ __forceinline__ float dot16_bias(
    const float (&h)[Hn], const float* __restrict__ w, float bias)
{
    float s0 = bias, s1 = 0.0f, s2 = 0.0f, s3 = 0.0f;
#pragma unroll
    for (int k = 0; k < Hn; k += 4) {
        s0 = fmaf(h[k + 0], w[k + 0], s0);
        s1 = fmaf(h[k + 1], w[k + 1], s1);
        s2 = fmaf(h[k + 2], w[k + 2], s2);
        s3 = fmaf(h[k + 3], w[k + 3], s3);
    }
    return (s0 + s1) + (s2 + s3);
}

// One full 128B-aligned L2 line (32 floats), back-to-back.
__device__ __forceinline__ void store_pair(
    float* __restrict__ dst, const float (&he)[Hn], const float (&ho)[Hn])
{
    float4* p = (float4*)dst;
    p[0] = make_float4(he[0],  he[1],  he[2],  he[3]);
    p[1] = make_float4(he[4],  he[5],  he[6],  he[7]);
    p[2] = make_float4(he[8],  he[9],  he[10], he[11]);
    p[3] = make_float4(he[12], he[13], he[14], he[15]);
    p[4] = make_float4(ho[0],  ho[1],  ho[2],  ho[3]);
    p[5] = make_float4(ho[4],  ho[5],  ho[6],  ho[7]);
    p[6] = make_float4(ho[8],  ho[9],  ho[10], ho[11]);
    p[7] = make_float4(ho[12], ho[13], ho[14], ho[15]);
}

__global__ __launch_bounds__(256)
__attribute__((amdgpu_waves_per_eu(4, 4)))  // clamp max occupancy -> 128-VGPR budget, no spills
void gru_adder_kernel(
    const float* __restrict__ x_bits,   // [B, 4, 2]
    const float* __restrict__ w_ih,     // [48, 2]
    const float* __restrict__ w_hh,     // [48, 16]
    const float* __restrict__ b_ih,     // [48]
    const float* __restrict__ b_hh,     // [48]
    const float* __restrict__ w_sum,    // [1, 16]
    const float* __restrict__ b_sum,    // [1]
    const float* __restrict__ w_carry,  // [1, 16]
    const float* __restrict__ b_carry,  // [1]
    float* __restrict__ out)            // [64B | 4B | B | 5B] floats
{
    const long long g  = (long long)blockIdx.x * blockDim.x + threadIdx.x;
    const long long b0 = 2 * g;  // batch elements b0 and b0+1

    // 16 consecutive x floats: both elements' full sequences, 64B/lane.
    const float4* xp = (const float4*)(x_bits + b0 * 8);
    const float4 v0 = xp[0], v1 = xp[1];  // elem A: t0..t3
    const float4 v2 = xp[2], v3 = xp[3];  // elem B: t0..t3

    const float bs = b_sum[0];

    float ha[Hn], hb[Hn];

    // ---- t = 0 (h == 0 specialization) ----
    gru_step0(v0.x, v0.y, w_ih, b_ih, b_hh, ha);
    gru_step0(v2.x, v2.y, w_ih, b_ih, b_hh, hb);

    // sum-logit shift queues (q3=t0 .. q0=t3 after all 4 pushes)
    float saq0 = dot16_bias(ha, w_sum, bs), saq1, saq2, saq3;
    float sbq0 = dot16_bias(hb, w_sum, bs), sbq1, sbq2, sbq3;
    saq1 = saq2 = saq3 = 0.0f;
    sbq1 = sbq2 = sbq3 = 0.0f;

    // x shift-register queues (no runtime-indexed arrays).
    float qa0 = v0.z, qa1 = v0.w, qa2 = v1.x, qa3 = v1.y, qa4 = v1.z, qa5 = v1.w;
    float qb0 = v2.z, qb1 = v2.w, qb2 = v3.x, qb3 = v3.y, qb4 = v3.z, qb5 = v3.w;

    // ---- t = 1..3, rolled ----
#pragma unroll 1
    for (int t = 1; t < 4; ++t) {
        float na[Hn], nb[Hn];
        gru_step(qa0, qa1, w_ih, w_hh, b_ih, b_hh, ha, na);
        gru_step(qb0, qb1, w_ih, w_hh, b_ih, b_hh, hb, nb);

        // push sums
        saq3 = saq2; saq2 = saq1; saq1 = saq0; saq0 = dot16_bias(na, w_sum, bs);
        sbq3 = sbq2; sbq2 = sbq1; sbq1 = sbq0; sbq0 = dot16_bias(nb, w_sum, bs);

        if (t != 2) {
            // (h_{t-1}, h_t) for both elements: two full 128B lines.
            asm volatile("" ::: "memory");
            float* base = out + b0 * 64 + (t == 1 ? 0 : 32);
            store_pair(base,      ha, na);  // elem A line
            store_pair(base + 64, hb, nb);  // elem B line
        }

#pragma unroll
        for (int j = 0; j < Hn; ++j) { ha[j] = na[j]; hb[j] = nb[j]; }

        // advance x queues
        qa0 = qa2; qa1 = qa3; qa2 = qa4; qa3 = qa5;
        qb0 = qb2; qb1 = qb3; qb2 = qb4; qb3 = qb5;
    }

    // ---- carry logits from final h ----
    const float bc = b_carry[0];
    const float ca = dot16_bias(ha, w_carry, bc);
    const float cb = dot16_bias(hb, w_carry, bc);

    // sum_logits [B,4]: 8 contiguous floats/thread, 32B-aligned.
    float4* sp = (float4*)(out + 64ll * Bn + b0 * 4);
    sp[0] = make_float4(saq3, saq2, saq1, saq0);  // elem A: t0..t3
    sp[1] = make_float4(sbq3, sbq2, sbq1, sbq0);  // elem B: t0..t3

    // carry_logit [B,1]: float2, 8B-aligned.
    *(float2*)(out + 68ll * Bn + b0) = make_float2(ca, cb);

    // output_logits [B,5]: 10 contiguous floats/thread, 8B-aligned.
    float2* ol = (float2*)(out + 69ll * Bn + b0 * 5);
    ol[0] = make_float2(saq3, saq2);
    ol[1] = make_float2(saq1, saq0);
    ol[2] = make_float2(ca,   sbq3);
    ol[3] = make_float2(sbq2, sbq1);
    ol[4] = make_float2(sbq0, cb);
}

extern "C" void kernel_launch(void* const* d_in, const int* in_sizes, int n_in,
                              void* d_out, int out_size, void* d_ws, size_t ws_size,
                              hipStream_t stream) {
    const float* x_bits  = (const float*)d_in[0];
    const float* w_ih    = (const float*)d_in[1];
    const float* w_hh    = (const float*)d_in[2];
    const float* b_ih    = (const float*)d_in[3];
    const float* b_hh    = (const float*)d_in[4];
    const float* w_sum   = (const float*)d_in[5];
    const float* b_sum   = (const float*)d_in[6];
    const float* w_carry = (const float*)d_in[7];
    const float* b_carry = (const float*)d_in[8];
    float* out = (float*)d_out;

    const int block = 256;
    const long long threads = Bn / 2;                       // 2 elems/thread
    const int grid = (int)((threads + block - 1) / block);  // 2048
    gru_adder_kernel<<<grid, block, 0, stream>>>(
        x_bits, w_ih, w_hh, b_ih, b_hh, w_sum, b_sum, w_carry, b_carry, out);
}

// Round 5
// 496.657 us; speedup vs baseline: 1.6066x; 1.3097x over previous
//
#include <hip/hip_runtime.h>

// GRUAdder: B=1048576 sequences, T=4, I=2, H=16.
// v6: 1 element/thread, fully unrolled, ping-pong h buffers, fenced
// pair-buffered line-complete hidden stores, DEFAULT occupancy.
//
// Trajectory evidence:
//  - The allocator pins this kernel family at <=64 VGPRs no matter what
//    (launch_bounds(256,4) -> 64, waves_per_eu(4,4) -> 64). The 2-elem
//    version's ~110-float live state therefore spills ~200B/thread:
//    v5 FETCH excess ~120MB + WRITE excess ~230MB = scratch streaming
//    to HBM (524288 threads' scratch >> 32MB L2).
//  - 1-elem pair-buffered peak liveness ~55 floats: fits 64 VGPRs
//    spill-free AND allows 8 waves/SIMD (2x v5's latency hiding).
//  - Pair stores must be fenced on BOTH sides: v3 showed the allocator
//    will split/sink the burst to shave liveness, re-creating the
//    write-allocate RMW fetch (partial 128B lines -> L2 fetches the
//    line on store miss; v3: 479MB fetch, 1.16GB write).

constexpr long long Bn = 1048576;
constexpr int Hn = 16;

__device__ __forceinline__ float sigm_f(float x) {
    return __builtin_amdgcn_rcpf(1.0f + __expf(-x));
}
__device__ __forceinline__ float tanh_f(float x) {
    return 1.0f - 2.0f * __builtin_amdgcn_rcpf(1.0f + __expf(2.0f * x));
}

// t = 0 step (h == 0): gh == b_hh, skips the 768 h@W_hh FMAs.
__device__ __forceinline__ void gru_step0(
    float x0, float x1,
    const float* __restrict__ w_ih, const float* __restrict__ b_ih,
    const float* __restrict__ b_hh, float (&h)[Hn])
{
#pragma unroll
    for (int j = 0; j < Hn; ++j) {
        const float ir  = fmaf(x1, w_ih[(j)      * 2 + 1], fmaf(x0, w_ih[(j)      * 2], b_ih[j]));
        const float iz  = fmaf(x1, w_ih[(16 + j) * 2 + 1], fmaf(x0, w_ih[(16 + j) * 2], b_ih[16 + j]));
        const float inn = fmaf(x1, w_ih[(32 + j) * 2 + 1], fmaf(x0, w_ih[(32 + j) * 2], b_ih[32 + j]));
        const float r = sigm_f(ir + b_hh[j]);
        const float z = sigm_f(iz + b_hh[16 + j]);
        const float n = tanh_f(fmaf(r, b_hh[32 + j], inn));
        h[j] = n - z * n;  // (1-z)*n + z*0
    }
}

// Full GRU step: hn = GRUCell(x, h).  hn must be a different array than h.
__device__ __forceinline__ void gru_step(
    float x0, float x1,
    const float* __restrict__ w_ih, const float* __restrict__ w_hh,
    const float* __restrict__ b_ih, const float* __restrict__ b_hh,
    const float (&h)[Hn], float (&hn)[Hn])
{
#pragma unroll
    for (int j = 0; j < Hn; ++j) {
        const float ir  = fmaf(x1, w_ih[(j)      * 2 + 1], fmaf(x0, w_ih[(j)      * 2], b_ih[j]));
        const float iz  = fmaf(x1, w_ih[(16 + j) * 2 + 1], fmaf(x0, w_ih[(16 + j) * 2], b_ih[16 + j]));
        const float inn = fmaf(x1, w_ih[(32 + j) * 2 + 1], fmaf(x0, w_ih[(32 + j) * 2], b_ih[32 + j]));
        float hr = b_hh[j];
        float hz = b_hh[16 + j];
        float hg = b_hh[32 + j];
#pragma unroll
        for (int k = 0; k < Hn; ++k) {
            const float hk = h[k];
            hr = fmaf(hk, w_hh[(j)      * 16 + k], hr);
            hz = fmaf(hk, w_hh[(16 + j) * 16 + k], hz);
            hg = fmaf(hk, w_hh[(32 + j) * 16 + k], hg);
        }
        const float r = sigm_f(ir + hr);
        const float z = sigm_f(iz + hz);
        const float n = tanh_f(fmaf(r, hg, inn));
        hn[j] = fmaf(z, h[j] - n, n);  // (1-z)*n + z*h
    }
}

__device__ __forceinline__ float dot16_bias(
    const float (&h)[Hn], const float* __restrict__ w, float bias)
{
    float s0 = bias, s1 = 0.0f, s2 = 0.0f, s3 = 0.0f;
#pragma unroll
    for (int k = 0; k < Hn; k += 4) {
        s0 = fmaf(h[k + 0], w[k + 0], s0);
        s1 = fmaf(h[k + 1], w[k + 1], s1);
        s2 = fmaf(h[k + 2], w[k + 2], s2);
        s3 = fmaf(h[k + 3], w[k + 3], s3);
    }
    return (s0 + s1) + (s2 + s3);
}

// One full 128B-aligned L2 line (32 floats), back-to-back, fenced so the
// scheduler can neither hoist it nor split/sink pieces of it.
__device__ __forceinline__ void store_pair_fenced(
    float* __restrict__ dst, const float (&he)[Hn], const float (&ho)[Hn])
{
    float4* p = (float4*)dst;
    asm volatile("" ::: "memory");
    p[0] = make_float4(he[0],  he[1],  he[2],  he[3]);
    p[1] = make_float4(he[4],  he[5],  he[6],  he[7]);
    p[2] = make_float4(he[8],  he[9],  he[10], he[11]);
    p[3] = make_float4(he[12], he[13], he[14], he[15]);
    p[4] = make_float4(ho[0],  ho[1],  ho[2],  ho[3]);
    p[5] = make_float4(ho[4],  ho[5],  ho[6],  ho[7]);
    p[6] = make_float4(ho[8],  ho[9],  ho[10], ho[11]);
    p[7] = make_float4(ho[12], ho[13], ho[14], ho[15]);
    asm volatile("" ::: "memory");
}

__global__ __launch_bounds__(256) void gru_adder_kernel(
    const float* __restrict__ x_bits,   // [B, 4, 2]
    const float* __restrict__ w_ih,     // [48, 2]
    const float* __restrict__ w_hh,     // [48, 16]
    const float* __restrict__ b_ih,     // [48]
    const float* __restrict__ b_hh,     // [48]
    const float* __restrict__ w_sum,    // [1, 16]
    const float* __restrict__ b_sum,    // [1]
    const float* __restrict__ w_carry,  // [1, 16]
    const float* __restrict__ b_carry,  // [1]
    float* __restrict__ out)            // [64B | 4B | B | 5B] floats
{
    const long long b = (long long)blockIdx.x * blockDim.x + threadIdx.x;

    // This sequence's 8 input floats (32B-aligned, two float4).
    const float4* xp = (const float4*)(x_bits + b * 8);
    const float4 xv0 = xp[0];
    const float4 xv1 = xp[1];

    const float bs = b_sum[0];

    float ha[Hn], hb[Hn];  // ping-pong: ha/hb alternate as h_{t-1} / h_t

    // ---- t = 0 (h == 0 specialization) -> ha ----
    gru_step0(xv0.x, xv0.y, w_ih, b_ih, b_hh, ha);
    const float s0 = dot16_bias(ha, w_sum, bs);

    // ---- t = 1: ha -> hb ----
    gru_step(xv0.z, xv0.w, w_ih, w_hh, b_ih, b_hh, ha, hb);
    const float s1 = dot16_bias(hb, w_sum, bs);

    // hidden_table[b][0..1][:] — one full 128B line, fenced burst.
    store_pair_fenced(out + b * 64, ha, hb);

    // ---- t = 2: hb -> ha (h0 is dead, reuse the buffer) ----
    gru_step(xv1.x, xv1.y, w_ih, w_hh, b_ih, b_hh, hb, ha);
    const float s2 = dot16_bias(ha, w_sum, bs);

    // ---- t = 3: ha -> hb ----
    gru_step(xv1.z, xv1.w, w_ih, w_hh, b_ih, b_hh, ha, hb);
    const float s3 = dot16_bias(hb, w_sum, bs);

    // hidden_table[b][2..3][:] — second full 128B line, fenced burst.
    store_pair_fenced(out + b * 64 + 32, ha, hb);

    // carry logit from final h (hb == h3)
    const float c = dot16_bias(hb, w_carry, b_carry[0]);

    // sum_logits [B,4] at 64*Bn — float4/lane, 16B stride, coalesced.
    *(float4*)(out + 64ll * Bn + b * 4) = make_float4(s0, s1, s2, s3);

    // carry_logit [B,1] at 68*Bn — 4B/lane, coalesced.
    out[68ll * Bn + b] = c;

    // output_logits [B,5] at 69*Bn — 5 contiguous floats/thread; the wave
    // covers a contiguous 1280B region, lines complete.
    float* ol = out + 69ll * Bn + b * 5;
    ol[0] = s0;
    ol[1] = s1;
    ol[2] = s2;
    ol[3] = s3;
    ol[4] = c;
}

extern "C" void kernel_launch(void* const* d_in, const int* in_sizes, int n_in,
                              void* d_out, int out_size, void* d_ws, size_t ws_size,
                              hipStream_t stream) {
    const float* x_bits  = (const float*)d_in[0];
    const float* w_ih    = (const float*)d_in[1];
    const float* w_hh    = (const float*)d_in[2];
    const float* b_ih    = (const float*)d_in[3];
    const float* b_hh    = (const float*)d_in[4];
    const float* w_sum   = (const float*)d_in[5];
    const float* b_sum   = (const float*)d_in[6];
    const float* w_carry = (const float*)d_in[7];
    const float* b_carry = (const float*)d_in[8];
    float* out = (float*)d_out;

    const int block = 256;
    const int grid = (int)((Bn + block - 1) / block);  // 4096
    gru_adder_kernel<<<grid, block, 0, stream>>>(
        x_bits, w_ih, w_hh, b_ih, b_hh, w_sum, b_sum, w_carry, b_carry, out);
}